// Round 7
// baseline (482.986 us; speedup 1.0000x reference)
//
#include <hip/hip_runtime.h>
#include <hip/hip_bf16.h>
#include <stdint.h>

#define TT 4096
#define DM 128
#define DIN 256
#define NB 4

typedef __attribute__((ext_vector_type(4))) float f32x4;
typedef __attribute__((ext_vector_type(8))) short s16x8;
typedef __attribute__((ext_vector_type(4))) short s16x4;
typedef __attribute__((ext_vector_type(4))) int i32x4;

union v4u { i32x4 u; s16x8 h; };

__device__ __forceinline__ unsigned short f2bf(float f) {
    union { float f; unsigned int u; } v; v.f = f;
    return (unsigned short)((v.u + 0x7FFFu + ((v.u >> 16) & 1u)) >> 16);
}

// ---------------- kernel 0: W (256x128 f32) -> Wt bf16 [3][128][256] ----------------
__global__ __launch_bounds__(256) void k_wt(const float* __restrict__ Wq,
                                            const float* __restrict__ Wk,
                                            const float* __restrict__ Wv,
                                            unsigned short* __restrict__ Wtb) {
    int tid = blockIdx.x * 256 + threadIdx.x;
    int m = tid >> 15;
    int r = tid & 32767;
    int n = r >> 8;
    int k = r & 255;
    const float* W = (m == 0) ? Wq : (m == 1) ? Wk : Wv;
    Wtb[(size_t)tid] = f2bf(W[k * DM + n]);
}

// ---------------- kernel 1: projections x@W+b -> Q/K/V bf16 [16384][128] ------------
__global__ __launch_bounds__(256) void k_proj(const float* __restrict__ x,
        const float* __restrict__ bq, const float* __restrict__ bk, const float* __restrict__ bv,
        const unsigned short* __restrict__ Wtb,
        unsigned short* __restrict__ Qb, unsigned short* __restrict__ Kb,
        unsigned short* __restrict__ Vb) {
    __shared__ __align__(16) unsigned short wt[DM][40];
    __shared__ __align__(16) unsigned short xl[64][40];
    int m = blockIdx.x >> 8;
    int tile = blockIdx.x & 255;
    int rowbase = tile * 64;
    int i = threadIdx.x;
    int w = i >> 6, l = i & 63;
    int lg = l >> 4, ll = l & 15;
    const float* bias = (m == 0) ? bq : (m == 1) ? bk : bv;
    unsigned short* out = (m == 0) ? Qb : (m == 1) ? Kb : Vb;
    const unsigned short* wsrc = Wtb + (size_t)m * DM * DIN;

    f32x4 acc[8];
    for (int n = 0; n < 8; n++) acc[n] = (f32x4){0.f, 0.f, 0.f, 0.f};

    for (int kk = 0; kk < 8; kk++) {
        int k0 = kk * 32;
        for (int t = 0; t < 2; t++) {
            int idx = i + t * 256;
            int row = idx >> 2, c8 = idx & 3;
            s16x8 v = *(const s16x8*)(wsrc + (size_t)row * DIN + k0 + c8 * 8);
            *(s16x8*)(&wt[row][c8 * 8]) = v;
        }
        for (int t = 0; t < 2; t++) {
            int idx = i + t * 256;
            int row = idx >> 3, c4 = idx & 7;
            f32x4 v = *(const f32x4*)(x + (size_t)(rowbase + row) * DIN + k0 + c4 * 4);
            s16x4 h;
            for (int j = 0; j < 4; j++) h[j] = (short)f2bf(v[j]);
            *(s16x4*)(&xl[row][c4 * 4]) = h;
        }
        __syncthreads();
        s16x8 a = *(const s16x8*)(&xl[w * 16 + ll][lg * 8]);
        for (int n = 0; n < 8; n++) {
            s16x8 b = *(const s16x8*)(&wt[n * 16 + ll][lg * 8]);
            acc[n] = __builtin_amdgcn_mfma_f32_16x16x32_bf16(a, b, acc[n], 0, 0, 0);
        }
        __syncthreads();
    }
    for (int n = 0; n < 8; n++) {
        int col = n * 16 + ll;
        float bv_ = bias[col];
        for (int j = 0; j < 4; j++) {
            int row = rowbase + w * 16 + lg * 4 + j;
            out[(size_t)row * DM + col] = f2bf(acc[n][j] + bv_);
        }
    }
}

// ---------------- kernel 2: V [b][t][d] -> Vt [b][d][t] (bf16) ----------------------
__global__ __launch_bounds__(256) void k_vt(const unsigned short* __restrict__ Vb,
                                            unsigned short* __restrict__ Vtb) {
    __shared__ __align__(16) unsigned short tile[64][72];
    int bid = blockIdx.x;
    int b = bid >> 7;
    int rem = bid & 127;
    int tI = rem >> 1, dI = rem & 1;
    int t0 = tI * 64, d0 = dI * 64;
    int i = threadIdx.x;
    for (int t = 0; t < 2; t++) {
        int idx = i + t * 256;
        int r = idx >> 3, c8 = idx & 7;
        s16x8 v = *(const s16x8*)(Vb + ((size_t)(b * TT) + t0 + r) * DM + d0 + c8 * 8);
        *(s16x8*)(&tile[r][c8 * 8]) = v;
    }
    __syncthreads();
    for (int t = 0; t < 2; t++) {
        int idx = i + t * 256;
        int r2 = idx >> 3, c8 = idx & 7;
        s16x8 v;
        for (int j = 0; j < 8; j++) v[j] = (short)tile[c8 * 8 + j][r2];
        *(s16x8*)(Vtb + ((size_t)b * DM + d0 + r2) * TT + t0 + c8 * 8) = v;
    }
}

// ---------------- kernel 3: attention, swapped-QK, LDS-free loops --------------------
// grid 512 (4 b x 128 rowtiles of 32), block 512 = 8 waves: rg=w&1 (16 rows),
// ks=w>>1 (16-key slice of each 64-key tile). No LDS in loops; K/V direct from L2.
// Swapped MFMA: acc = mfma(Kfrag, Qfrag) -> lane holds P[qrow=ll][keys lg*4+j].
__global__ __launch_bounds__(512, 4) void k_attn(const unsigned short* __restrict__ Qb,
        const unsigned short* __restrict__ Kb, const unsigned short* __restrict__ Vtb,
        float* __restrict__ outO, float* __restrict__ outA) {
    __shared__ __align__(16) float rsx[8 * 16];            // 512 B
    __shared__ __align__(16) float obuf[6 * 16 * 132];     // 50688 B

    int bid = blockIdx.x;
    int id2 = (bid & 7) * 64 + (bid >> 3);   // XCD swizzle: batch's K/V pinned to 2 XCDs
    int b = id2 >> 7;
    int rowbase = (id2 & 127) * 32;
    int i = threadIdx.x;
    int w = i >> 6, l = i & 63;
    int rg = w & 1, ks = w >> 1;
    int lg = l >> 4, ll = l & 15;

    const unsigned short* Qrow = Qb + ((size_t)(b * TT) + rowbase) * DM;
    const unsigned short* Krow = Kb + (size_t)(b * TT) * DM;
    const unsigned short* Vt_b = Vtb + (size_t)b * DM * TT;
    const float scale = 0.08838834764831845f;  // 1/sqrt(128)

    // Q fragments (B-operand): lane (lg,ll) holds Q[rg*16+ll][c*32+lg*8 ..+7]
    s16x8 qf[4];
    for (int c = 0; c < 4; c++)
        qf[c] = *(const s16x8*)(Qrow + (size_t)(rg * 16 + ll) * DM + c * 32 + lg * 8);

    // K fragment base (A-operand): key row = s0 + ks*16 + ll
    const unsigned short* Kfl = Krow + (size_t)(ks * 16 + ll) * DM + lg * 8;

    // ================= phase 1: rowsums of exp(S), reg double-buffered ==============
    float rs = 0.f;
    {
        s16x8 ka[4], kb_[4];
        for (int c = 0; c < 4; c++) ka[c] = *(const s16x8*)(Kfl + c * 32);
        for (int t = 0; t < 64; t += 2) {
            const unsigned short* kn = Kfl + (size_t)(t + 1) * 64 * DM;
            for (int c = 0; c < 4; c++) kb_[c] = *(const s16x8*)(kn + c * 32);
            f32x4 acc = (f32x4){0.f, 0.f, 0.f, 0.f};
            for (int c = 0; c < 4; c++)
                acc = __builtin_amdgcn_mfma_f32_16x16x32_bf16(ka[c], qf[c], acc, 0, 0, 0);
            for (int j = 0; j < 4; j++) rs += __expf(acc[j] * scale);
            int t2 = (t + 2 < 64) ? t + 2 : t;
            const unsigned short* kn2 = Kfl + (size_t)t2 * 64 * DM;
            for (int c = 0; c < 4; c++) ka[c] = *(const s16x8*)(kn2 + c * 32);
            acc = (f32x4){0.f, 0.f, 0.f, 0.f};
            for (int c = 0; c < 4; c++)
                acc = __builtin_amdgcn_mfma_f32_16x16x32_bf16(kb_[c], qf[c], acc, 0, 0, 0);
            for (int j = 0; j < 4; j++) rs += __expf(acc[j] * scale);
        }
    }
    // rs now = partial rowsum for qrow (rg*16+ll) over this lane's keys; sum over lg
    rs += __shfl_xor(rs, 16, 64);
    rs += __shfl_xor(rs, 32, 64);
    if (lg == 0) rsx[w * 16 + ll] = rs;
    __syncthreads();
    float inv = 1.0f / (rsx[(0 * 2 + rg) * 16 + ll] + rsx[(1 * 2 + rg) * 16 + ll]
                      + rsx[(2 * 2 + rg) * 16 + ll] + rsx[(3 * 2 + rg) * 16 + ll]);

    // ================= phase 2: recompute S, write attn (f32), O = P@V ==============
    f32x4 oacc[8];
    for (int n = 0; n < 8; n++) oacc[n] = (f32x4){0.f, 0.f, 0.f, 0.f};

    const unsigned short* Vfl = Vt_b + (size_t)ll * TT + ks * 16 + (lg & 1) * 8;
    float* Arow = outA + ((size_t)(b * TT) + rowbase + rg * 16 + ll) * TT + ks * 16 + lg * 4;
    int a0addr = (((2 * lg) & 3) * 16 + ll) * 4;
    int a1addr = (((2 * lg + 1) & 3) * 16 + ll) * 4;

    for (int t = 0; t < 64; t++) {
        size_t s0 = (size_t)t * 64;
        // K loads, then QK (wait drains only iter-old stores, overlapped with flight)
        s16x8 kf[4];
        const unsigned short* kp = Kfl + s0 * DM;
        for (int c = 0; c < 4; c++) kf[c] = *(const s16x8*)(kp + c * 32);
        f32x4 acc = (f32x4){0.f, 0.f, 0.f, 0.f};
        for (int c = 0; c < 4; c++)
            acc = __builtin_amdgcn_mfma_f32_16x16x32_bf16(kf[c], qf[c], acc, 0, 0, 0);
        // V loads (issued before any dependent wait; lg>=2 duplicates lg&1 rows, x0)
        s16x8 vf[8];
        const unsigned short* vp = Vfl + s0;
        for (int n = 0; n < 8; n++)
            vf[n] = *(const s16x8*)(vp + (size_t)n * 16 * TT);
        // softmax + attn store straight from registers (f32, nontemporal)
        f32x4 p;
        for (int j = 0; j < 4; j++) p[j] = __expf(acc[j] * scale) * inv;
        __builtin_nontemporal_store(p, (f32x4*)(Arow + s0));
        // pack to bf16 + in-register A-fragment assembly via bpermute
        unsigned u0 = (unsigned)f2bf(p[0]) | ((unsigned)f2bf(p[1]) << 16);
        unsigned u1 = (unsigned)f2bf(p[2]) | ((unsigned)f2bf(p[3]) << 16);
        int b0 = __builtin_amdgcn_ds_bpermute(a0addr, (int)u0);
        int b1 = __builtin_amdgcn_ds_bpermute(a0addr, (int)u1);
        int b2 = __builtin_amdgcn_ds_bpermute(a1addr, (int)u0);
        int b3 = __builtin_amdgcn_ds_bpermute(a1addr, (int)u1);
        v4u pa;
        pa.u = (lg < 2) ? (i32x4){b0, b1, b2, b3} : (i32x4){0, 0, 0, 0};
        // PV: A = P (k 0..15 real, 16..31 zero), B = V
        for (int n = 0; n < 8; n++)
            oacc[n] = __builtin_amdgcn_mfma_f32_16x16x32_bf16(pa.h, vf[n], oacc[n], 0, 0, 0);
    }

    // ================= O reduction across 4 key-slice waves ==========================
    if (ks > 0) {
        float* dst = obuf + (size_t)(rg * 3 + ks - 1) * 16 * 132;
        for (int n = 0; n < 8; n++)
            for (int j = 0; j < 4; j++)
                dst[(lg * 4 + j) * 132 + n * 16 + ll] = oacc[n][j];
    }
    __syncthreads();
    if (ks == 0) {
        float* d0 = obuf + (size_t)(rg * 3 + 0) * 16 * 132;
        float* d1 = obuf + (size_t)(rg * 3 + 1) * 16 * 132;
        float* d2 = obuf + (size_t)(rg * 3 + 2) * 16 * 132;
        for (int n = 0; n < 8; n++)
            for (int j = 0; j < 4; j++) {
                int idx = (lg * 4 + j) * 132 + n * 16 + ll;
                d0[idx] = oacc[n][j] + d0[idx] + d1[idx] + d2[idx];
            }
    }
    __syncthreads();
    // cooperative coalesced outO store
    {
        int row = i >> 4;            // 0..31
        int col = (i & 15) * 8;      // 0..120
        const float* src = obuf + (size_t)((row >> 4) * 3) * 16 * 132 + (row & 15) * 132 + col;
        f32x4 v0 = *(const f32x4*)(src);
        f32x4 v1 = *(const f32x4*)(src + 4);
        float* dst = outO + ((size_t)(b * TT) + rowbase + row) * DM + col;
        *(f32x4*)dst = v0;
        *(f32x4*)(dst + 4) = v1;
    }
}

extern "C" void kernel_launch(void* const* d_in, const int* in_sizes, int n_in,
                              void* d_out, int out_size, void* d_ws, size_t ws_size,
                              hipStream_t stream) {
    const float* x  = (const float*)d_in[0];
    const float* Wq = (const float*)d_in[1];
    const float* bq = (const float*)d_in[2];
    const float* Wk = (const float*)d_in[3];
    const float* bk = (const float*)d_in[4];
    const float* Wv = (const float*)d_in[5];
    const float* bv = (const float*)d_in[6];
    float* outO = (float*)d_out;
    float* outA = outO + (size_t)NB * TT * DM;

    char* ws = (char*)d_ws;
    unsigned short* Qb  = (unsigned short*)(ws);
    unsigned short* Kb  = (unsigned short*)(ws + ((size_t)1 << 22));
    unsigned short* Vb  = (unsigned short*)(ws + ((size_t)2 << 22));
    unsigned short* Vtb = (unsigned short*)(ws + ((size_t)3 << 22));
    unsigned short* Wtb = (unsigned short*)(ws + ((size_t)4 << 22));

    k_wt<<<dim3(384), dim3(256), 0, stream>>>(Wq, Wk, Wv, Wtb);
    k_proj<<<dim3(768), dim3(256), 0, stream>>>(x, bq, bk, bv, Wtb, Qb, Kb, Vb);
    k_vt<<<dim3(512), dim3(256), 0, stream>>>(Vb, Vtb);
    k_attn<<<dim3(512), dim3(512), 0, stream>>>(Qb, Kb, Vtb, outO, outA);
}

// Round 8
// 145.256 us; speedup vs baseline: 3.3251x; 3.3251x over previous
//
#include <hip/hip_runtime.h>
#include <hip/hip_bf16.h>
#include <stdint.h>

#define TT 4096
#define DM 128
#define DIN 256
#define NB 4

typedef __attribute__((ext_vector_type(4))) float f32x4;
typedef __attribute__((ext_vector_type(8))) short s16x8;
typedef __attribute__((ext_vector_type(4))) short s16x4;
typedef __attribute__((ext_vector_type(4))) int i32x4;

union v4u { i32x4 u; s16x8 h; };

__device__ __forceinline__ unsigned short f2bf(float f) {
    union { float f; unsigned int u; } v; v.f = f;
    return (unsigned short)((v.u + 0x7FFFu + ((v.u >> 16) & 1u)) >> 16);
}

// async global->LDS, 16B/lane, dest = wave-uniform base + lane*16
__device__ __forceinline__ void cp16(const void* g, void* l) {
    __builtin_amdgcn_global_load_lds(
        (__attribute__((address_space(1))) unsigned int*)(size_t)g,
        (__attribute__((address_space(3))) unsigned int*)l, 16, 0, 0);
}

// ---------------- kernel 0: W (256x128 f32) -> Wt bf16 [3][128][256] ----------------
__global__ __launch_bounds__(256) void k_wt(const float* __restrict__ Wq,
                                            const float* __restrict__ Wk,
                                            const float* __restrict__ Wv,
                                            unsigned short* __restrict__ Wtb) {
    int tid = blockIdx.x * 256 + threadIdx.x;
    int m = tid >> 15;
    int r = tid & 32767;
    int n = r >> 8;
    int k = r & 255;
    const float* W = (m == 0) ? Wq : (m == 1) ? Wk : Wv;
    Wtb[(size_t)tid] = f2bf(W[k * DM + n]);
}

// ---------------- kernel 1: projections x@W+b -> Q/K/V bf16 [16384][128] ------------
__global__ __launch_bounds__(256) void k_proj(const float* __restrict__ x,
        const float* __restrict__ bq, const float* __restrict__ bk, const float* __restrict__ bv,
        const unsigned short* __restrict__ Wtb,
        unsigned short* __restrict__ Qb, unsigned short* __restrict__ Kb,
        unsigned short* __restrict__ Vb) {
    __shared__ __align__(16) unsigned short wt[DM][40];
    __shared__ __align__(16) unsigned short xl[64][40];
    int m = blockIdx.x >> 8;
    int tile = blockIdx.x & 255;
    int rowbase = tile * 64;
    int i = threadIdx.x;
    int w = i >> 6, l = i & 63;
    int lg = l >> 4, ll = l & 15;
    const float* bias = (m == 0) ? bq : (m == 1) ? bk : bv;
    unsigned short* out = (m == 0) ? Qb : (m == 1) ? Kb : Vb;
    const unsigned short* wsrc = Wtb + (size_t)m * DM * DIN;

    f32x4 acc[8];
    for (int n = 0; n < 8; n++) acc[n] = (f32x4){0.f, 0.f, 0.f, 0.f};

    for (int kk = 0; kk < 8; kk++) {
        int k0 = kk * 32;
        for (int t = 0; t < 2; t++) {
            int idx = i + t * 256;
            int row = idx >> 2, c8 = idx & 3;
            s16x8 v = *(const s16x8*)(wsrc + (size_t)row * DIN + k0 + c8 * 8);
            *(s16x8*)(&wt[row][c8 * 8]) = v;
        }
        for (int t = 0; t < 2; t++) {
            int idx = i + t * 256;
            int row = idx >> 3, c4 = idx & 7;
            f32x4 v = *(const f32x4*)(x + (size_t)(rowbase + row) * DIN + k0 + c4 * 4);
            s16x4 h;
            for (int j = 0; j < 4; j++) h[j] = (short)f2bf(v[j]);
            *(s16x4*)(&xl[row][c4 * 4]) = h;
        }
        __syncthreads();
        s16x8 a = *(const s16x8*)(&xl[w * 16 + ll][lg * 8]);
        for (int n = 0; n < 8; n++) {
            s16x8 b = *(const s16x8*)(&wt[n * 16 + ll][lg * 8]);
            acc[n] = __builtin_amdgcn_mfma_f32_16x16x32_bf16(a, b, acc[n], 0, 0, 0);
        }
        __syncthreads();
    }
    for (int n = 0; n < 8; n++) {
        int col = n * 16 + ll;
        float bv_ = bias[col];
        for (int j = 0; j < 4; j++) {
            int row = rowbase + w * 16 + lg * 4 + j;
            out[(size_t)row * DM + col] = f2bf(acc[n][j] + bv_);
        }
    }
}

// ---------------- kernel 2: V [b][t][d] -> Vt [b][d][t] (bf16) ----------------------
__global__ __launch_bounds__(256) void k_vt(const unsigned short* __restrict__ Vb,
                                            unsigned short* __restrict__ Vtb) {
    __shared__ __align__(16) unsigned short tile[64][72];
    int bid = blockIdx.x;
    int b = bid >> 7;
    int rem = bid & 127;
    int tI = rem >> 1, dI = rem & 1;
    int t0 = tI * 64, d0 = dI * 64;
    int i = threadIdx.x;
    for (int t = 0; t < 2; t++) {
        int idx = i + t * 256;
        int r = idx >> 3, c8 = idx & 7;
        s16x8 v = *(const s16x8*)(Vb + ((size_t)(b * TT) + t0 + r) * DM + d0 + c8 * 8);
        *(s16x8*)(&tile[r][c8 * 8]) = v;
    }
    __syncthreads();
    for (int t = 0; t < 2; t++) {
        int idx = i + t * 256;
        int r2 = idx >> 3, c8 = idx & 7;
        s16x8 v;
        for (int j = 0; j < 8; j++) v[j] = (short)tile[c8 * 8 + j][r2];
        *(s16x8*)(Vtb + ((size_t)b * DM + d0 + r2) * TT + t0 + c8 * 8) = v;
    }
}

// ---------------- kernel 3: attention = R3 staging + R7 swapped-QK -------------------
// grid 512 (4 b x 128 rowtiles of 32), block 512 = 8 waves: rg=w&1 (16 rows),
// ks=w>>1 (16-key slice of each 64-key tile).
// K/V async-staged (cp16, XOR-swizzled source); ONE barrier + vmcnt per tile.
// Swapped MFMA: acc = mfma(Kfrag, Qfrag) -> lane holds P[qrow=ll][keys lg*4+j];
// attn stored as one f32x4/lane from registers; PV A-frag via 4 ds_bpermute.
__global__ __launch_bounds__(512, 4) void k_attn(const unsigned short* __restrict__ Qb,
        const unsigned short* __restrict__ Kb, const unsigned short* __restrict__ Vtb,
        float* __restrict__ outO, float* __restrict__ outA) {
    __shared__ __align__(16) char smem[66048];
    // ring: 4 x 16KB (phase1: K ring-4; phase2: K dbuf at 0/16384, V dbuf at 32768/49152)
    // rsx: f32[128] at 65536; obuf aliases ring after loops.

    int bid = blockIdx.x;
    int id2 = (bid & 7) * 64 + (bid >> 3);   // XCD swizzle (512%8==0, bijective)
    int b = id2 >> 7;
    int rowbase = (id2 & 127) * 32;
    int i = threadIdx.x;
    int w = i >> 6, l = i & 63;
    int rg = w & 1, ks = w >> 1;
    int lg = l >> 4, ll = l & 15;

    const unsigned short* Qrow = Qb + ((size_t)(b * TT) + rowbase) * DM;
    const unsigned short* Krow = Kb + (size_t)(b * TT) * DM;
    const unsigned short* Vt_b = Vtb + (size_t)b * DM * TT;
    const float scale = 0.08838834764831845f;  // 1/sqrt(128)

    float* rsx = (float*)(smem + 65536);

    // Q fragment (B-operand): lane (lg,ll) holds Q[rg*16+ll][c*32+lg*8 ..+7]
    s16x8 qf[4];
    for (int c = 0; c < 4; c++)
        qf[c] = *(const s16x8*)(Qrow + (size_t)(rg * 16 + ll) * DM + c * 32 + lg * 8);

    int kr = ks * 16 + ll;   // K LDS row this lane reads

    auto stage_k = [&](char* kbuf, int s0) {
        for (int u = 0; u < 2; u++) {
            int ch = u * 8 + w;
            int row = ch * 4 + (l >> 4);
            int g = (l & 15) ^ (row & 7);
            cp16(Krow + (size_t)(s0 + row) * DM + g * 8, kbuf + ch * 1024);
        }
    };
    auto stage_v = [&](char* vbuf, int s0) {
        for (int u = 0; u < 2; u++) {
            int ch = u * 8 + w;
            int row = ch * 8 + (l >> 3);
            int g = (l & 7) ^ (row & 7);
            cp16(Vt_b + (size_t)row * TT + s0 + g * 8, vbuf + ch * 1024);
        }
    };
    auto qk = [&](const char* kbuf) -> f32x4 {
        const char* kbase = kbuf + kr * 256;
        f32x4 acc = (f32x4){0.f, 0.f, 0.f, 0.f};
        for (int c = 0; c < 4; c++) {
            s16x8 kf = *(const s16x8*)(kbase + (((c * 4 + lg) ^ (kr & 7)) << 4));
            acc = __builtin_amdgcn_mfma_f32_16x16x32_bf16(kf, qf[c], acc, 0, 0, 0);
        }
        return acc;
    };

    // ================= phase 1: rowsums of exp(S); K ring-4, depth-2 ================
    float rs = 0.f;
    stage_k(smem, 0);
    stage_k(smem + 16384, 64);
    asm volatile("s_waitcnt vmcnt(2)" ::: "memory");
    __builtin_amdgcn_s_barrier();
    for (int t = 0; t < 64; t++) {
        if (t + 2 < 64) stage_k(smem + ((t + 2) & 3) * 16384, (t + 2) * 64);
        asm volatile("" ::: "memory");
        f32x4 acc = qk(smem + (t & 3) * 16384);
        for (int j = 0; j < 4; j++) rs += __expf(acc[j] * scale);
        if (t + 2 < 64) asm volatile("s_waitcnt vmcnt(2)" ::: "memory");
        else            asm volatile("s_waitcnt vmcnt(0)" ::: "memory");
        __builtin_amdgcn_s_barrier();
    }
    // rs = partial rowsum for qrow (rg*16+ll) over this lane's keys; reduce over lg
    rs += __shfl_xor(rs, 16, 64);
    rs += __shfl_xor(rs, 32, 64);
    if (lg == 0) rsx[w * 16 + ll] = rs;
    __syncthreads();
    float inv = 1.0f / (rsx[(0 * 2 + rg) * 16 + ll] + rsx[(1 * 2 + rg) * 16 + ll]
                      + rsx[(2 * 2 + rg) * 16 + ll] + rsx[(3 * 2 + rg) * 16 + ll]);

    // ================= phase 2: recompute S, write attn, O = P@V ====================
    f32x4 oacc[8];
    for (int n = 0; n < 8; n++) oacc[n] = (f32x4){0.f, 0.f, 0.f, 0.f};

    float* Arow = outA + ((size_t)(b * TT) + rowbase + rg * 16 + ll) * TT + ks * 16 + lg * 4;
    int a0addr = (((2 * lg) & 3) * 16 + ll) * 4;
    int a1addr = (((2 * lg + 1) & 3) * 16 + ll) * 4;
    int gi = ks * 2 + (lg & 1);

    stage_k(smem, 0);
    stage_v(smem + 32768, 0);
    asm volatile("s_waitcnt vmcnt(0)" ::: "memory");
    __builtin_amdgcn_s_barrier();

    for (int t = 0; t < 64; t++) {
        size_t s0 = (size_t)t * 64;
        if (t < 63) {   // stage next tile FIRST (oldest in vmcnt queue)
            stage_k(smem + ((t + 1) & 1) * 16384, t * 64 + 64);
            stage_v(smem + 32768 + ((t + 1) & 1) * 16384, t * 64 + 64);
        }
        asm volatile("" ::: "memory");   // pin cp16 issue ahead of the attn store
        // QK^T (bit-identical chain to phase 1)
        f32x4 acc = qk(smem + (t & 1) * 16384);
        // softmax + attn store straight from registers (f32x4, nontemporal)
        f32x4 p;
        for (int j = 0; j < 4; j++) p[j] = __expf(acc[j] * scale) * inv;
        __builtin_nontemporal_store(p, (f32x4*)(Arow + s0));
        // pack to bf16 + in-register PV A-fragment via bpermute (R7-validated)
        unsigned u0 = (unsigned)f2bf(p[0]) | ((unsigned)f2bf(p[1]) << 16);
        unsigned u1 = (unsigned)f2bf(p[2]) | ((unsigned)f2bf(p[3]) << 16);
        int b0 = __builtin_amdgcn_ds_bpermute(a0addr, (int)u0);
        int b1 = __builtin_amdgcn_ds_bpermute(a0addr, (int)u1);
        int b2 = __builtin_amdgcn_ds_bpermute(a1addr, (int)u0);
        int b3 = __builtin_amdgcn_ds_bpermute(a1addr, (int)u1);
        v4u pa;
        pa.u = (lg < 2) ? (i32x4){b0, b1, b2, b3} : (i32x4){0, 0, 0, 0};
        // PV: A = P (k 0..15 real keys of this ks-slice, 16..31 zero), B = V from LDS
        const char* vbuf = smem + 32768 + (t & 1) * 16384;
        for (int n = 0; n < 8; n++) {
            int vr = n * 16 + ll;
            s16x8 bfr = *(const s16x8*)(vbuf + vr * 128 + ((gi ^ (vr & 7)) << 4));
            oacc[n] = __builtin_amdgcn_mfma_f32_16x16x32_bf16(pa.h, bfr, oacc[n], 0, 0, 0);
        }
        asm volatile("s_waitcnt vmcnt(1)" ::: "memory");  // stage drained; store lingers
        __builtin_amdgcn_s_barrier();
    }

    // ================= O reduction across 4 key-slice waves =========================
    float* obuf = (float*)smem;   // [6][16][132] f32, aliases ring (dead)
    if (ks > 0) {
        float* dst = obuf + (size_t)(rg * 3 + ks - 1) * 16 * 132;
        for (int n = 0; n < 8; n++)
            for (int j = 0; j < 4; j++)
                dst[(lg * 4 + j) * 132 + n * 16 + ll] = oacc[n][j];
    }
    __syncthreads();
    if (ks == 0) {
        float* d0 = obuf + (size_t)(rg * 3 + 0) * 16 * 132;
        float* d1 = obuf + (size_t)(rg * 3 + 1) * 16 * 132;
        float* d2 = obuf + (size_t)(rg * 3 + 2) * 16 * 132;
        for (int n = 0; n < 8; n++)
            for (int j = 0; j < 4; j++) {
                int idx = (lg * 4 + j) * 132 + n * 16 + ll;
                d0[idx] = oacc[n][j] + d0[idx] + d1[idx] + d2[idx];
            }
    }
    __syncthreads();
    // cooperative coalesced outO store
    {
        int row = i >> 4;            // 0..31
        int col = (i & 15) * 8;      // 0..120
        const float* src = obuf + (size_t)((row >> 4) * 3) * 16 * 132 + (row & 15) * 132 + col;
        f32x4 v0 = *(const f32x4*)(src);
        f32x4 v1 = *(const f32x4*)(src + 4);
        float* dst = outO + ((size_t)(b * TT) + rowbase + row) * DM + col;
        *(f32x4*)dst = v0;
        *(f32x4*)(dst + 4) = v1;
    }
}

extern "C" void kernel_launch(void* const* d_in, const int* in_sizes, int n_in,
                              void* d_out, int out_size, void* d_ws, size_t ws_size,
                              hipStream_t stream) {
    const float* x  = (const float*)d_in[0];
    const float* Wq = (const float*)d_in[1];
    const float* bq = (const float*)d_in[2];
    const float* Wk = (const float*)d_in[3];
    const float* bk = (const float*)d_in[4];
    const float* Wv = (const float*)d_in[5];
    const float* bv = (const float*)d_in[6];
    float* outO = (float*)d_out;
    float* outA = outO + (size_t)NB * TT * DM;

    char* ws = (char*)d_ws;
    unsigned short* Qb  = (unsigned short*)(ws);
    unsigned short* Kb  = (unsigned short*)(ws + ((size_t)1 << 22));
    unsigned short* Vb  = (unsigned short*)(ws + ((size_t)2 << 22));
    unsigned short* Vtb = (unsigned short*)(ws + ((size_t)3 << 22));
    unsigned short* Wtb = (unsigned short*)(ws + ((size_t)4 << 22));

    k_wt<<<dim3(384), dim3(256), 0, stream>>>(Wq, Wk, Wv, Wtb);
    k_proj<<<dim3(768), dim3(256), 0, stream>>>(x, bq, bk, bv, Wtb, Qb, Kb, Vb);
    k_vt<<<dim3(512), dim3(256), 0, stream>>>(Vb, Vtb);
    k_attn<<<dim3(512), dim3(512), 0, stream>>>(Qb, Kb, Vtb, outO, outA);
}

// Round 9
// 137.193 us; speedup vs baseline: 3.5205x; 1.0588x over previous
//
#include <hip/hip_runtime.h>
#include <hip/hip_bf16.h>
#include <stdint.h>

#define TT 4096
#define DM 128
#define DIN 256
#define NB 4

typedef __attribute__((ext_vector_type(4))) float f32x4;
typedef __attribute__((ext_vector_type(8))) short s16x8;
typedef __attribute__((ext_vector_type(4))) short s16x4;
typedef __attribute__((ext_vector_type(2))) unsigned int u32x2;

__device__ __forceinline__ unsigned short f2bf(float f) {
    union { float f; unsigned int u; } v; v.f = f;
    return (unsigned short)((v.u + 0x7FFFu + ((v.u >> 16) & 1u)) >> 16);
}

// async global->LDS, 16B/lane, dest = wave-uniform base + lane*16
__device__ __forceinline__ void cp16(const void* g, void* l) {
    __builtin_amdgcn_global_load_lds(
        (__attribute__((address_space(1))) unsigned int*)(size_t)g,
        (__attribute__((address_space(3))) unsigned int*)l, 16, 0, 0);
}

// ---------------- kernel 0: W (256x128 f32) -> Wt bf16 [3][128][256] ----------------
__global__ __launch_bounds__(256) void k_wt(const float* __restrict__ Wq,
                                            const float* __restrict__ Wk,
                                            const float* __restrict__ Wv,
                                            unsigned short* __restrict__ Wtb) {
    int tid = blockIdx.x * 256 + threadIdx.x;
    int m = tid >> 15;
    int r = tid & 32767;
    int n = r >> 8;
    int k = r & 255;
    const float* W = (m == 0) ? Wq : (m == 1) ? Wk : Wv;
    Wtb[(size_t)tid] = f2bf(W[k * DM + n]);
}

// ---------------- kernel 1: projections x@W+b -> Q/K/V bf16 [16384][128] ------------
__global__ __launch_bounds__(256) void k_proj(const float* __restrict__ x,
        const float* __restrict__ bq, const float* __restrict__ bk, const float* __restrict__ bv,
        const unsigned short* __restrict__ Wtb,
        unsigned short* __restrict__ Qb, unsigned short* __restrict__ Kb,
        unsigned short* __restrict__ Vb) {
    __shared__ __align__(16) unsigned short wt[DM][40];
    __shared__ __align__(16) unsigned short xl[64][40];
    int m = blockIdx.x >> 8;
    int tile = blockIdx.x & 255;
    int rowbase = tile * 64;
    int i = threadIdx.x;
    int w = i >> 6, l = i & 63;
    int lg = l >> 4, ll = l & 15;
    const float* bias = (m == 0) ? bq : (m == 1) ? bk : bv;
    unsigned short* out = (m == 0) ? Qb : (m == 1) ? Kb : Vb;
    const unsigned short* wsrc = Wtb + (size_t)m * DM * DIN;

    f32x4 acc[8];
    for (int n = 0; n < 8; n++) acc[n] = (f32x4){0.f, 0.f, 0.f, 0.f};

    for (int kk = 0; kk < 8; kk++) {
        int k0 = kk * 32;
        for (int t = 0; t < 2; t++) {
            int idx = i + t * 256;
            int row = idx >> 2, c8 = idx & 3;
            s16x8 v = *(const s16x8*)(wsrc + (size_t)row * DIN + k0 + c8 * 8);
            *(s16x8*)(&wt[row][c8 * 8]) = v;
        }
        for (int t = 0; t < 2; t++) {
            int idx = i + t * 256;
            int row = idx >> 3, c4 = idx & 7;
            f32x4 v = *(const f32x4*)(x + (size_t)(rowbase + row) * DIN + k0 + c4 * 4);
            s16x4 h;
            for (int j = 0; j < 4; j++) h[j] = (short)f2bf(v[j]);
            *(s16x4*)(&xl[row][c4 * 4]) = h;
        }
        __syncthreads();
        s16x8 a = *(const s16x8*)(&xl[w * 16 + ll][lg * 8]);
        for (int n = 0; n < 8; n++) {
            s16x8 b = *(const s16x8*)(&wt[n * 16 + ll][lg * 8]);
            acc[n] = __builtin_amdgcn_mfma_f32_16x16x32_bf16(a, b, acc[n], 0, 0, 0);
        }
        __syncthreads();
    }
    for (int n = 0; n < 8; n++) {
        int col = n * 16 + ll;
        float bv_ = bias[col];
        for (int j = 0; j < 4; j++) {
            int row = rowbase + w * 16 + lg * 4 + j;
            out[(size_t)row * DM + col] = f2bf(acc[n][j] + bv_);
        }
    }
}

// ---------------- kernel 2: V [b][t][d] -> Vt [b][d][t] (bf16) ----------------------
__global__ __launch_bounds__(256) void k_vt(const unsigned short* __restrict__ Vb,
                                            unsigned short* __restrict__ Vtb) {
    __shared__ __align__(16) unsigned short tile[64][72];
    int bid = blockIdx.x;
    int b = bid >> 7;
    int rem = bid & 127;
    int tI = rem >> 1, dI = rem & 1;
    int t0 = tI * 64, d0 = dI * 64;
    int i = threadIdx.x;
    for (int t = 0; t < 2; t++) {
        int idx = i + t * 256;
        int r = idx >> 3, c8 = idx & 7;
        s16x8 v = *(const s16x8*)(Vb + ((size_t)(b * TT) + t0 + r) * DM + d0 + c8 * 8);
        *(s16x8*)(&tile[r][c8 * 8]) = v;
    }
    __syncthreads();
    for (int t = 0; t < 2; t++) {
        int idx = i + t * 256;
        int r2 = idx >> 3, c8 = idx & 7;
        s16x8 v;
        for (int j = 0; j < 8; j++) v[j] = (short)tile[c8 * 8 + j][r2];
        *(s16x8*)(Vtb + ((size_t)b * DM + d0 + r2) * TT + t0 + c8 * 8) = v;
    }
}

// ---------------- kernel 3: attention, producer/consumer wave split ------------------
// grid 512 (4 b x 128 rowtiles of 32), block 512 = 8 waves.
// Phase 1: all 8 waves compute rowsums of exp(S) (swapped QK, 64-key tiles, ring-3).
// Phase 2 (32-key tiles, 128 iters, ONE barrier/iter):
//   waves 0-3 (producers): stage K (ring-3), QK swapped, exp*inv, P -> LDS (f32 + bf16)
//   waves 4-7 (consumers): stage V (ring-4), PV(t-1) from P-bf16, attn-store(t-1)
//   P triple-buffered; per-role counted vmcnt (ledger-derived); stores never drained.
__global__ __launch_bounds__(512, 4) void k_attn(const unsigned short* __restrict__ Qb,
        const unsigned short* __restrict__ Kb, const unsigned short* __restrict__ Vtb,
        float* __restrict__ outO, float* __restrict__ outA) {
    __shared__ __align__(16) char smem[79360];
    // phase2: K ring-3 @0 (3x8192), V ring-4 @24576 (4x8192)
    // Pf (f32, [32][36]) 3x4608 @57344 ; Pb (u16, [32][40]) 3x2560 @71168
    // rsx f32[8][16] @78848.  phase1 ring-3 of 16KB @0 (disjoint from Pf/Pb/rsx).

    int bid = blockIdx.x;
    int id2 = (bid & 7) * 64 + (bid >> 3);   // XCD swizzle (512%8==0, bijective)
    int b = id2 >> 7;
    int rowbase = (id2 & 127) * 32;
    int i = threadIdx.x;
    int w = i >> 6, l = i & 63;
    int lg = l >> 4, ll = l & 15;
    int rh = w & 1;

    const unsigned short* Qrow = Qb + ((size_t)(b * TT) + rowbase) * DM;
    const unsigned short* Krow = Kb + (size_t)(b * TT) * DM;
    const unsigned short* Vt_b = Vtb + (size_t)b * DM * TT;
    const float scale = 0.08838834764831845f;  // 1/sqrt(128)

    float* rsx = (float*)(smem + 78848);

    // Q fragment (B-operand): lane (lg,ll) holds Q[rh*16+ll][c*32+lg*8 ..+7]
    s16x8 qf[4];
    for (int c = 0; c < 4; c++)
        qf[c] = *(const s16x8*)(Qrow + (size_t)(rh * 16 + ll) * DM + c * 32 + lg * 8);

    // ================= phase 1: rowsums of exp(S); 64-key tiles, ring-3 =============
    float rs = 0.f;
    {
        int ks = w >> 1;                 // 4 key-slices of 16
        int kr = ks * 16 + ll;
        auto stage1 = [&](int slot, int t) {
            int s0 = t * 64;
            for (int u = 0; u < 2; u++) {
                int c = u * 8 + w;
                int row = c * 4 + (l >> 4);
                int g = (l & 15) ^ (row & 7);
                cp16(Krow + (size_t)(s0 + row) * DM + g * 8, smem + slot * 16384 + c * 1024);
            }
        };
        stage1(0, 0); stage1(1, 1);
        asm volatile("s_waitcnt vmcnt(2)" ::: "memory");
        __builtin_amdgcn_s_barrier();
        int cur = 0, nxt = 2;
        for (int t = 0; t < 64; t++) {
            if (t + 2 < 64) stage1(nxt, t + 2);
            const char* kbase = smem + cur * 16384 + kr * 256;
            f32x4 acc = (f32x4){0.f, 0.f, 0.f, 0.f};
            for (int c = 0; c < 4; c++) {
                s16x8 kf = *(const s16x8*)(kbase + (((c * 4 + lg) ^ (kr & 7)) << 4));
                acc = __builtin_amdgcn_mfma_f32_16x16x32_bf16(kf, qf[c], acc, 0, 0, 0);
            }
            for (int j = 0; j < 4; j++) rs += __expf(acc[j] * scale);
            if (t + 2 < 64) asm volatile("s_waitcnt vmcnt(2)" ::: "memory");
            else            asm volatile("s_waitcnt vmcnt(0)" ::: "memory");
            __builtin_amdgcn_s_barrier();
            cur++; if (cur == 3) cur = 0;
            nxt++; if (nxt == 3) nxt = 0;
        }
    }
    rs += __shfl_xor(rs, 16, 64);
    rs += __shfl_xor(rs, 32, 64);
    if (l < 16) rsx[w * 16 + l] = rs;
    __syncthreads();
    float inv = 0.f;
    if (w < 4)
        inv = 1.0f / (rsx[rh * 16 + ll] + rsx[(2 + rh) * 16 + ll]
                    + rsx[(4 + rh) * 16 + ll] + rsx[(6 + rh) * 16 + ll]);

    // ================= phase 2 ======================================================
    char* kslotb = smem;                                    // 3 x 8192
    char* vslotb = smem + 24576;                            // 4 x 8192
    float* PfB = (float*)(smem + 57344);                    // 3 x 1152 f32
    unsigned short* PbB = (unsigned short*)(smem + 71168);  // 3 x 1280 u16

    f32x4 oacc[4];
    for (int n = 0; n < 4; n++) oacc[n] = (f32x4){0.f, 0.f, 0.f, 0.f};

    int kh = w >> 1;                 // producer key-half
    int kr2 = kh * 16 + ll;
    int cw = w - 4;                  // consumer index 0..3
    int r2 = cw & 1, c2 = cw >> 1;   // consumer PV quadrant

    auto stageK = [&](int slot, int t) {
        int s0 = t * 32;
        for (int u = 0; u < 2; u++) {
            int c = u * 4 + w;
            int row = c * 4 + (l >> 4);
            int g = (l & 15) ^ (row & 7);
            cp16(Krow + (size_t)(s0 + row) * DM + g * 8, kslotb + slot * 8192 + c * 1024);
        }
    };
    auto stageV = [&](int slot, int t) {
        int s0 = t * 32;
        for (int u = 0; u < 2; u++) {
            int c = u * 4 + cw;
            int row = c * 16 + (l >> 2);
            int g = (l & 3) ^ (row & 3);
            cp16(Vt_b + (size_t)row * TT + s0 + g * 8, vslotb + slot * 8192 + c * 1024);
        }
    };

    if (w < 4) { stageK(0, 0); stageK(1, 1);
                 asm volatile("s_waitcnt vmcnt(2)" ::: "memory"); }
    else       { stageV(0, 0); stageV(1, 1); }
    __syncthreads();

    // running slot indices
    int pk_cur = 0, pk_nxt = 2;        // producer: t%3, (t+2)%3
    int cP = 2, cV = 3, cVn = 2;       // consumer: (t-1)%3, (t-1)%4, (t+2)%4

    for (int t = 0; t < 128; t++) {
        if (w < 4) {
            // ---------------- producer ----------------
            if (t + 2 <= 127) stageK(pk_nxt, t + 2);
            const char* kbase = kslotb + pk_cur * 8192 + kr2 * 256;
            f32x4 acc = (f32x4){0.f, 0.f, 0.f, 0.f};
            for (int c = 0; c < 4; c++) {
                s16x8 kf = *(const s16x8*)(kbase + (((c * 4 + lg) ^ (kr2 & 7)) << 4));
                acc = __builtin_amdgcn_mfma_f32_16x16x32_bf16(kf, qf[c], acc, 0, 0, 0);
            }
            f32x4 p;
            for (int j = 0; j < 4; j++) p[j] = __expf(acc[j] * scale) * inv;
            int prow = rh * 16 + ll;
            *(f32x4*)(PfB + pk_cur * 1152 + prow * 36 + kh * 16 + lg * 4) = p;
            u32x2 pb;
            pb[0] = (unsigned)f2bf(p[0]) | ((unsigned)f2bf(p[1]) << 16);
            pb[1] = (unsigned)f2bf(p[2]) | ((unsigned)f2bf(p[3]) << 16);
            *(u32x2*)(PbB + pk_cur * 1280 + prow * 40 + kh * 16 + lg * 4) = pb;
            asm volatile("s_waitcnt lgkmcnt(0)" ::: "memory");
            if (t < 126) asm volatile("s_waitcnt vmcnt(2)" ::: "memory");
            else         asm volatile("s_waitcnt vmcnt(0)" ::: "memory");
            __builtin_amdgcn_s_barrier();
            pk_cur++; if (pk_cur == 3) pk_cur = 0;
            pk_nxt++; if (pk_nxt == 3) pk_nxt = 0;
        } else {
            // ---------------- consumer ----------------
            __builtin_amdgcn_s_barrier();
            if (t + 2 <= 127) stageV(cVn, t + 2);
            if (t < 2)        asm volatile("s_waitcnt vmcnt(4)" ::: "memory");
            else if (t < 126) asm volatile("s_waitcnt vmcnt(5)" ::: "memory");
            else if (t == 126) asm volatile("s_waitcnt vmcnt(3)" ::: "memory");
            else              asm volatile("s_waitcnt vmcnt(1)" ::: "memory");
            if (t >= 1) {
                // PV(t-1): A = P rows r2*16+ll (32 real keys), B = V quadrant
                s16x8 pa = *(const s16x8*)(PbB + cP * 1280 + (r2 * 16 + ll) * 40 + lg * 8);
                const char* vb = vslotb + cV * 8192;
                for (int n8 = 0; n8 < 4; n8++) {
                    int vr = c2 * 64 + n8 * 16 + ll;
                    s16x8 bf = *(const s16x8*)(vb + vr * 64 + ((lg ^ (vr & 3)) << 4));
                    oacc[n8] = __builtin_amdgcn_mfma_f32_16x16x32_bf16(pa, bf, oacc[n8], 0, 0, 0);
                }
                // attn store(t-1): 128B-contiguous row segments from Pf
                int arow = cw * 8 + (l >> 3);
                int acol = (l & 7) * 4;
                f32x4 av = *(const f32x4*)(PfB + cP * 1152 + arow * 36 + acol);
                __builtin_nontemporal_store(av,
                    (f32x4*)(outA + ((size_t)(b * TT) + rowbase + arow) * TT
                             + (size_t)(t - 1) * 32 + acol));
            }
            cP++; if (cP == 3) cP = 0;
            cV++; if (cV == 4) cV = 0;
            cVn++; if (cVn == 4) cVn = 0;
        }
    }

    // epilogue: consumers finish tile 127 (P slot 127%3=1, V slot 127%4=3), store O
    if (w >= 4) {
        s16x8 pa = *(const s16x8*)(PbB + 1 * 1280 + (r2 * 16 + ll) * 40 + lg * 8);
        const char* vb = vslotb + 3 * 8192;
        for (int n8 = 0; n8 < 4; n8++) {
            int vr = c2 * 64 + n8 * 16 + ll;
            s16x8 bf = *(const s16x8*)(vb + vr * 64 + ((lg ^ (vr & 3)) << 4));
            oacc[n8] = __builtin_amdgcn_mfma_f32_16x16x32_bf16(pa, bf, oacc[n8], 0, 0, 0);
        }
        {
            int arow = cw * 8 + (l >> 3);
            int acol = (l & 7) * 4;
            f32x4 av = *(const f32x4*)(PfB + 1 * 1152 + arow * 36 + acol);
            __builtin_nontemporal_store(av,
                (f32x4*)(outA + ((size_t)(b * TT) + rowbase + arow) * TT
                         + (size_t)127 * 32 + acol));
        }
        // O: each consumer owns quadrant rows r2*16.., cols c2*64..
        for (int n8 = 0; n8 < 4; n8++)
            for (int j = 0; j < 4; j++) {
                int row = r2 * 16 + lg * 4 + j;
                int col = c2 * 64 + n8 * 16 + ll;
                outO[((size_t)(b * TT) + rowbase + row) * DM + col] = oacc[n8][j];
            }
    }
}

extern "C" void kernel_launch(void* const* d_in, const int* in_sizes, int n_in,
                              void* d_out, int out_size, void* d_ws, size_t ws_size,
                              hipStream_t stream) {
    const float* x  = (const float*)d_in[0];
    const float* Wq = (const float*)d_in[1];
    const float* bq = (const float*)d_in[2];
    const float* Wk = (const float*)d_in[3];
    const float* bk = (const float*)d_in[4];
    const float* Wv = (const float*)d_in[5];
    const float* bv = (const float*)d_in[6];
    float* outO = (float*)d_out;
    float* outA = outO + (size_t)NB * TT * DM;

    char* ws = (char*)d_ws;
    unsigned short* Qb  = (unsigned short*)(ws);
    unsigned short* Kb  = (unsigned short*)(ws + ((size_t)1 << 22));
    unsigned short* Vb  = (unsigned short*)(ws + ((size_t)2 << 22));
    unsigned short* Vtb = (unsigned short*)(ws + ((size_t)3 << 22));
    unsigned short* Wtb = (unsigned short*)(ws + ((size_t)4 << 22));

    k_wt<<<dim3(384), dim3(256), 0, stream>>>(Wq, Wk, Wv, Wtb);
    k_proj<<<dim3(768), dim3(256), 0, stream>>>(x, bq, bk, bv, Wtb, Qb, Kb, Vb);
    k_vt<<<dim3(512), dim3(256), 0, stream>>>(Vb, Vtb);
    k_attn<<<dim3(512), dim3(512), 0, stream>>>(Qb, Kb, Vtb, outO, outA);
}

// Round 10
// 133.709 us; speedup vs baseline: 3.6122x; 1.0261x over previous
//
#include <hip/hip_runtime.h>
#include <hip/hip_bf16.h>
#include <stdint.h>

#define TT 4096
#define DM 128
#define DIN 256
#define NB 4

typedef __attribute__((ext_vector_type(4))) float f32x4;
typedef __attribute__((ext_vector_type(8))) short s16x8;
typedef __attribute__((ext_vector_type(4))) short s16x4;
typedef __attribute__((ext_vector_type(2))) unsigned int u32x2;

__device__ __forceinline__ unsigned short f2bf(float f) {
    union { float f; unsigned int u; } v; v.f = f;
    return (unsigned short)((v.u + 0x7FFFu + ((v.u >> 16) & 1u)) >> 16);
}
__device__ __forceinline__ float bf2f(unsigned short h) {
    union { unsigned int u; float f; } v; v.u = ((unsigned int)h) << 16;
    return v.f;
}

// async global->LDS, 16B/lane, dest = wave-uniform base + lane*16
__device__ __forceinline__ void cp16(const void* g, void* l) {
    __builtin_amdgcn_global_load_lds(
        (__attribute__((address_space(1))) unsigned int*)(size_t)g,
        (__attribute__((address_space(3))) unsigned int*)l, 16, 0, 0);
}

// ---------------- kernel 0: W (256x128 f32) -> Wt bf16 [3][128][256] ----------------
__global__ __launch_bounds__(256) void k_wt(const float* __restrict__ Wq,
                                            const float* __restrict__ Wk,
                                            const float* __restrict__ Wv,
                                            unsigned short* __restrict__ Wtb) {
    int tid = blockIdx.x * 256 + threadIdx.x;
    int m = tid >> 15;
    int r = tid & 32767;
    int n = r >> 8;
    int k = r & 255;
    const float* W = (m == 0) ? Wq : (m == 1) ? Wk : Wv;
    Wtb[(size_t)tid] = f2bf(W[k * DM + n]);
}

// ---------------- kernel 1: projections x@W+b -> Q/K/V bf16 [16384][128] ------------
__global__ __launch_bounds__(256) void k_proj(const float* __restrict__ x,
        const float* __restrict__ bq, const float* __restrict__ bk, const float* __restrict__ bv,
        const unsigned short* __restrict__ Wtb,
        unsigned short* __restrict__ Qb, unsigned short* __restrict__ Kb,
        unsigned short* __restrict__ Vb) {
    __shared__ __align__(16) unsigned short wt[DM][40];
    __shared__ __align__(16) unsigned short xl[64][40];
    int m = blockIdx.x >> 8;
    int tile = blockIdx.x & 255;
    int rowbase = tile * 64;
    int i = threadIdx.x;
    int w = i >> 6, l = i & 63;
    int lg = l >> 4, ll = l & 15;
    const float* bias = (m == 0) ? bq : (m == 1) ? bk : bv;
    unsigned short* out = (m == 0) ? Qb : (m == 1) ? Kb : Vb;
    const unsigned short* wsrc = Wtb + (size_t)m * DM * DIN;

    f32x4 acc[8];
    for (int n = 0; n < 8; n++) acc[n] = (f32x4){0.f, 0.f, 0.f, 0.f};

    for (int kk = 0; kk < 8; kk++) {
        int k0 = kk * 32;
        for (int t = 0; t < 2; t++) {
            int idx = i + t * 256;
            int row = idx >> 2, c8 = idx & 3;
            s16x8 v = *(const s16x8*)(wsrc + (size_t)row * DIN + k0 + c8 * 8);
            *(s16x8*)(&wt[row][c8 * 8]) = v;
        }
        for (int t = 0; t < 2; t++) {
            int idx = i + t * 256;
            int row = idx >> 3, c4 = idx & 7;
            f32x4 v = *(const f32x4*)(x + (size_t)(rowbase + row) * DIN + k0 + c4 * 4);
            s16x4 h;
            for (int j = 0; j < 4; j++) h[j] = (short)f2bf(v[j]);
            *(s16x4*)(&xl[row][c4 * 4]) = h;
        }
        __syncthreads();
        s16x8 a = *(const s16x8*)(&xl[w * 16 + ll][lg * 8]);
        for (int n = 0; n < 8; n++) {
            s16x8 b = *(const s16x8*)(&wt[n * 16 + ll][lg * 8]);
            acc[n] = __builtin_amdgcn_mfma_f32_16x16x32_bf16(a, b, acc[n], 0, 0, 0);
        }
        __syncthreads();
    }
    for (int n = 0; n < 8; n++) {
        int col = n * 16 + ll;
        float bv_ = bias[col];
        for (int j = 0; j < 4; j++) {
            int row = rowbase + w * 16 + lg * 4 + j;
            out[(size_t)row * DM + col] = f2bf(acc[n][j] + bv_);
        }
    }
}

// ---------------- kernel 2: V [b][t][d] -> Vt [b][d][t] (bf16) ----------------------
__global__ __launch_bounds__(256) void k_vt(const unsigned short* __restrict__ Vb,
                                            unsigned short* __restrict__ Vtb) {
    __shared__ __align__(16) unsigned short tile[64][72];
    int bid = blockIdx.x;
    int b = bid >> 7;
    int rem = bid & 127;
    int tI = rem >> 1, dI = rem & 1;
    int t0 = tI * 64, d0 = dI * 64;
    int i = threadIdx.x;
    for (int t = 0; t < 2; t++) {
        int idx = i + t * 256;
        int r = idx >> 3, c8 = idx & 7;
        s16x8 v = *(const s16x8*)(Vb + ((size_t)(b * TT) + t0 + r) * DM + d0 + c8 * 8);
        *(s16x8*)(&tile[r][c8 * 8]) = v;
    }
    __syncthreads();
    for (int t = 0; t < 2; t++) {
        int idx = i + t * 256;
        int r2 = idx >> 3, c8 = idx & 7;
        s16x8 v;
        for (int j = 0; j < 8; j++) v[j] = (short)tile[c8 * 8 + j][r2];
        *(s16x8*)(Vtb + ((size_t)b * DM + d0 + r2) * TT + t0 + c8 * 8) = v;
    }
}

// ---------------- kernel A: rowsums of exp(S), key-split (R5-validated) -------------
// grid 2048 = 4 b x 128 rowtiles x 4 kq; block 256 = 4 waves (rg=w&1, ks=w>>1).
// Output: rsum8[b][kq*2+ks][4096] f32 partials (deterministic, no atomics).
__global__ __launch_bounds__(256, 6) void k_rowsum(const unsigned short* __restrict__ Qb,
        const unsigned short* __restrict__ Kb, float* __restrict__ rsum8) {
    __shared__ __align__(16) char smem[24576];   // 3 x 8KB K slots

    int bid = blockIdx.x;
    int id2 = (bid & 7) * 256 + (bid >> 3);     // XCD swizzle (2048%8==0)
    int b = id2 >> 9;
    int rem = id2 & 511;
    int rt = rem >> 2, kq = rem & 3;
    int rowbase = rt * 32;
    int i = threadIdx.x;
    int w = i >> 6, l = i & 63;
    int rg = w & 1, ks = w >> 1;
    int lg = l >> 4, ll = l & 15;

    const unsigned short* Qrow = Qb + ((size_t)(b * TT) + rowbase) * DM;
    const unsigned short* Krow = Kb + (size_t)(b * TT) * DM + (size_t)(kq * 1024) * DM;
    const float scale = 0.08838834764831845f;

    s16x8 qf[4];
    for (int c = 0; c < 4; c++)
        qf[c] = *(const s16x8*)(Qrow + (size_t)(rg * 16 + ll) * DM + c * 32 + lg * 8);

    int kr = ks * 16 + ll;
    auto stage = [&](char* kbuf, int t) {
        int s0 = t * 32;
        for (int u = 0; u < 2; u++) {
            int c = u * 4 + w;
            int row = c * 4 + (l >> 4);
            int g = (l & 15) ^ (row & 7);
            cp16(Krow + (size_t)(s0 + row) * DM + g * 8, kbuf + c * 1024);
        }
    };

    float rs[4] = {0.f, 0.f, 0.f, 0.f};
    stage(smem, 0);
    stage(smem + 8192, 1);
    asm volatile("s_waitcnt vmcnt(2)" ::: "memory");
    __builtin_amdgcn_s_barrier();

    int cur = 0, nxt = 2;
    for (int t = 0; t < 32; t++) {
        int tn = (t + 2 <= 31) ? t + 2 : 31;
        stage(smem + nxt * 8192, tn);
        const char* kbase = smem + cur * 8192 + kr * 256;
        f32x4 a0 = (f32x4){0.f, 0.f, 0.f, 0.f}, a1 = (f32x4){0.f, 0.f, 0.f, 0.f};
        {
            s16x8 k0 = *(const s16x8*)(kbase + (((0 * 4 + lg) ^ (kr & 7)) << 4));
            s16x8 k1 = *(const s16x8*)(kbase + (((1 * 4 + lg) ^ (kr & 7)) << 4));
            s16x8 k2 = *(const s16x8*)(kbase + (((2 * 4 + lg) ^ (kr & 7)) << 4));
            s16x8 k3 = *(const s16x8*)(kbase + (((3 * 4 + lg) ^ (kr & 7)) << 4));
            a0 = __builtin_amdgcn_mfma_f32_16x16x32_bf16(qf[0], k0, a0, 0, 0, 0);
            a1 = __builtin_amdgcn_mfma_f32_16x16x32_bf16(qf[1], k1, a1, 0, 0, 0);
            a0 = __builtin_amdgcn_mfma_f32_16x16x32_bf16(qf[2], k2, a0, 0, 0, 0);
            a1 = __builtin_amdgcn_mfma_f32_16x16x32_bf16(qf[3], k3, a1, 0, 0, 0);
        }
        f32x4 acc;
        for (int j = 0; j < 4; j++) acc[j] = a0[j] + a1[j];
        for (int j = 0; j < 4; j++) rs[j] += __expf(acc[j] * scale);
        asm volatile("s_waitcnt vmcnt(2)" ::: "memory");
        __builtin_amdgcn_s_barrier();
        cur++; if (cur == 3) cur = 0;
        nxt++; if (nxt == 3) nxt = 0;
    }
    for (int mm = 1; mm < 16; mm <<= 1)
        for (int j = 0; j < 4; j++) rs[j] += __shfl_xor(rs[j], mm, 64);
    if (ll == 0) {
        int p = kq * 2 + ks;
        float* dst = rsum8 + ((size_t)(b * 8 + p)) * TT + rowbase + rg * 16 + lg * 4;
        for (int j = 0; j < 4; j++) dst[j] = rs[j];
    }
}

// ---------------- kernel B: phase-2 only, p/c waves, barrier per 2 tiles ------------
// grid 512 (4 b x 128 rowtiles of 32), block 512 = 8 waves.
// waves 0-3 producers: stage K (ring-4, ahead-2), QK swapped per tile, exp*inv,
//                      P bf16 -> LDS ring-4.
// waves 4-7 consumers: stage V (ring-4, window-ahead), PV(lag-2) + attn store.
// 64 windows x 2 tiles; ONE barrier per window; counted vmcnt, stores never drained.
__global__ __launch_bounds__(512, 4) void k_attn2(const unsigned short* __restrict__ Qb,
        const unsigned short* __restrict__ Kb, const unsigned short* __restrict__ Vtb,
        const float* __restrict__ rsum8,
        float* __restrict__ outO, float* __restrict__ outA) {
    __shared__ __align__(16) char smem[75776];
    // K: 4x8192 @0 ; V: 4x8192 @32768 ; Pb: 4x2560 ([32][40] u16) @65536

    int bid = blockIdx.x;
    int id2 = (bid & 7) * 64 + (bid >> 3);   // XCD swizzle (512%8==0, bijective)
    int b = id2 >> 7;
    int rowbase = (id2 & 127) * 32;
    int i = threadIdx.x;
    int w = i >> 6, l = i & 63;
    int lg = l >> 4, ll = l & 15;
    int rh = w & 1;

    const unsigned short* Qrow = Qb + ((size_t)(b * TT) + rowbase) * DM;
    const unsigned short* Krow = Kb + (size_t)(b * TT) * DM;
    const unsigned short* Vt_b = Vtb + (size_t)b * DM * TT;
    const float scale = 0.08838834764831845f;

    char* kslotb = smem;
    char* vslotb = smem + 32768;
    unsigned short* PbB = (unsigned short*)(smem + 65536);

    int kh = w >> 1;                 // producer key-half (0..1 over waves 0-3)
    int kr2 = kh * 16 + ll;
    int cw = w - 4;                  // consumer index 0..3
    int r2 = cw & 1, c2 = cw >> 1;   // consumer PV quadrant

    auto stageK = [&](int slot, int t) {
        int s0 = t * 32;
        for (int u = 0; u < 2; u++) {
            int c = u * 4 + w;
            int row = c * 4 + (l >> 4);
            int g = (l & 15) ^ (row & 7);
            cp16(Krow + (size_t)(s0 + row) * DM + g * 8, kslotb + slot * 8192 + c * 1024);
        }
    };
    auto stageV = [&](int slot, int t) {
        int s0 = t * 32;
        for (int u = 0; u < 2; u++) {
            int c = u * 4 + cw;
            int row = c * 16 + (l >> 2);
            int g = (l & 3) ^ (row & 3);
            cp16(Vt_b + (size_t)row * TT + s0 + g * 8, vslotb + slot * 8192 + c * 1024);
        }
    };

    if (w < 4) {
        // =============================== producer =================================
        s16x8 qf[4];
        for (int c = 0; c < 4; c++)
            qf[c] = *(const s16x8*)(Qrow + (size_t)(rh * 16 + ll) * DM + c * 32 + lg * 8);
        float inv;
        {
            int row = rowbase + rh * 16 + ll;
            float s = 0.f;
            for (int p = 0; p < 8; p++) s += rsum8[((size_t)(b * 8 + p)) * TT + row];
            inv = 1.0f / s;
        }
        stageK(0, 0); stageK(1, 1);
        asm volatile("s_waitcnt vmcnt(0)" ::: "memory");
        __builtin_amdgcn_s_barrier();                         // rendezvous #0

        for (int wd = 0; wd < 64; wd++) {
            int t0 = 2 * wd;
            if (wd < 63) { stageK((t0 + 2) & 3, t0 + 2); stageK((t0 + 3) & 3, t0 + 3); }
            for (int s = 0; s < 2; s++) {
                int t = t0 + s;
                const char* kbase = kslotb + (t & 3) * 8192 + kr2 * 256;
                f32x4 acc = (f32x4){0.f, 0.f, 0.f, 0.f};
                __builtin_amdgcn_s_setprio(1);
                for (int c = 0; c < 4; c++) {
                    s16x8 kf = *(const s16x8*)(kbase + (((c * 4 + lg) ^ (kr2 & 7)) << 4));
                    acc = __builtin_amdgcn_mfma_f32_16x16x32_bf16(kf, qf[c], acc, 0, 0, 0);
                }
                __builtin_amdgcn_s_setprio(0);
                f32x4 p;
                for (int j = 0; j < 4; j++) p[j] = __expf(acc[j] * scale) * inv;
                int prow = rh * 16 + ll;
                u32x2 pb;
                pb[0] = (unsigned)f2bf(p[0]) | ((unsigned)f2bf(p[1]) << 16);
                pb[1] = (unsigned)f2bf(p[2]) | ((unsigned)f2bf(p[3]) << 16);
                *(u32x2*)(PbB + (t & 3) * 1280 + prow * 40 + kh * 16 + lg * 4) = pb;
            }
            asm volatile("s_waitcnt lgkmcnt(0)" ::: "memory");
            asm volatile("s_waitcnt vmcnt(0)" ::: "memory");  // only own cp16s queued
            __builtin_amdgcn_s_barrier();                     // rendezvous #wd+1
        }
    } else {
        // =============================== consumer =================================
        f32x4 oacc[4];
        for (int n = 0; n < 4; n++) oacc[n] = (f32x4){0.f, 0.f, 0.f, 0.f};

        auto ctile = [&](int u) {
            unsigned short* Pslot = PbB + (u & 3) * 1280;
            s16x8 pa = *(const s16x8*)(Pslot + (r2 * 16 + ll) * 40 + lg * 8);
            const char* vb = vslotb + (u & 3) * 8192;
            __builtin_amdgcn_s_setprio(1);
            for (int n8 = 0; n8 < 4; n8++) {
                int vr = c2 * 64 + n8 * 16 + ll;
                s16x8 bf = *(const s16x8*)(vb + vr * 64 + ((lg ^ (vr & 3)) << 4));
                oacc[n8] = __builtin_amdgcn_mfma_f32_16x16x32_bf16(pa, bf, oacc[n8], 0, 0, 0);
            }
            __builtin_amdgcn_s_setprio(0);
            int arow = cw * 8 + (l >> 3);
            int acol = (l & 7) * 4;
            s16x4 pv = *(const s16x4*)(Pslot + arow * 40 + acol);
            f32x4 fv;
            for (int q = 0; q < 4; q++) fv[q] = bf2f((unsigned short)pv[q]);
            __builtin_nontemporal_store(fv,
                (f32x4*)(outA + ((size_t)(b * TT) + rowbase + arow) * TT
                         + (size_t)u * 32 + acol));
        };

        for (int wd = 0; wd < 64; wd++) {
            __builtin_amdgcn_s_barrier();                     // rendezvous #wd
            int t0 = 2 * wd;
            stageV(t0 & 3, t0); stageV((t0 + 1) & 3, t0 + 1);
            if (wd == 1)      asm volatile("s_waitcnt vmcnt(4)" ::: "memory");
            else if (wd >= 2) asm volatile("s_waitcnt vmcnt(6)" ::: "memory");
            if (wd >= 1) { ctile(t0 - 2); ctile(t0 - 1); }
        }
        __builtin_amdgcn_s_barrier();                         // rendezvous #64
        asm volatile("s_waitcnt vmcnt(0)" ::: "memory");
        ctile(126); ctile(127);

        // O store: each consumer owns quadrant rows r2*16.., cols c2*64..
        for (int n8 = 0; n8 < 4; n8++)
            for (int j = 0; j < 4; j++) {
                int row = r2 * 16 + lg * 4 + j;
                int col = c2 * 64 + n8 * 16 + ll;
                outO[((size_t)(b * TT) + rowbase + row) * DM + col] = oacc[n8][j];
            }
    }
}

extern "C" void kernel_launch(void* const* d_in, const int* in_sizes, int n_in,
                              void* d_out, int out_size, void* d_ws, size_t ws_size,
                              hipStream_t stream) {
    const float* x  = (const float*)d_in[0];
    const float* Wq = (const float*)d_in[1];
    const float* bq = (const float*)d_in[2];
    const float* Wk = (const float*)d_in[3];
    const float* bk = (const float*)d_in[4];
    const float* Wv = (const float*)d_in[5];
    const float* bv = (const float*)d_in[6];
    float* outO = (float*)d_out;
    float* outA = outO + (size_t)NB * TT * DM;

    char* ws = (char*)d_ws;
    unsigned short* Qb  = (unsigned short*)(ws);
    unsigned short* Kb  = (unsigned short*)(ws + ((size_t)1 << 22));
    unsigned short* Vb  = (unsigned short*)(ws + ((size_t)2 << 22));
    unsigned short* Vtb = (unsigned short*)(ws + ((size_t)3 << 22));
    unsigned short* Wtb = (unsigned short*)(ws + ((size_t)4 << 22));
    float* rsum8 = (float*)(ws + ((size_t)5 << 22));

    k_wt<<<dim3(384), dim3(256), 0, stream>>>(Wq, Wk, Wv, Wtb);
    k_proj<<<dim3(768), dim3(256), 0, stream>>>(x, bq, bk, bv, Wtb, Qb, Kb, Vb);
    k_vt<<<dim3(512), dim3(256), 0, stream>>>(Vb, Vtb);
    k_rowsum<<<dim3(2048), dim3(256), 0, stream>>>(Qb, Kb, rsum8);
    k_attn2<<<dim3(512), dim3(512), 0, stream>>>(Qb, Kb, Vtb, rsum8, outO, outA);
}